// Round 17
// baseline (1590.177 us; speedup 1.0000x reference)
//
#include <hip/hip_runtime.h>
#include <hip/hip_fp16.h>

// GRU (Keras reset_after=True), B=64 T=512 D=256 H=1024.
// Persistent kernel, 256 WGs (1/CU), weights register-resident.
// Single-hop packet protocol (LLC/sc0sc1): packets are 8 native f16 + 4-bit
// seq nibble stolen from dword3 LSBs; full-packet serial spin where the
// passing iteration IS the data (R13, champion at 967us).
// R17: single surgical edit vs R13 -- x(t+1) loads issued AFTER the poll
// breaks, so the poll's vmcnt(0) drains ONLY packet loads (x loads were
// adding ~300-400cy of L3 latency to every step's first-sweep detect).

#define NB 64
#define NT 512
#define ND 256
#define NH 1024
#define NG 3072  // 3H

typedef _Float16 f16;
typedef __attribute__((ext_vector_type(8))) _Float16 f16x8;
typedef __attribute__((ext_vector_type(4))) float f32x4;
typedef __attribute__((ext_vector_type(4))) unsigned int u32x4;

// ---- prep: pack U [H,3H] f32 -> B-fragment-layout f16 ----
__global__ void pack_u_kernel(const float* __restrict__ U, f16* __restrict__ Up) {
    int idx = blockIdx.x * 256 + threadIdx.x;      // 393216
    int l  = idx & 63;
    int kt = (idx >> 6) & 31;
    int r  = idx >> 11;                            // jb*3 + g
    int g  = r % 3, jb = r / 3;
    int col = g * NH + jb * 16 + (l & 15);
    int k0  = kt * 32 + (l >> 4) * 8;
    f16x8 v;
#pragma unroll
    for (int e = 0; e < 8; ++e) v[e] = (f16)U[(size_t)(k0 + e) * NG + col];
    *(f16x8*)(Up + (size_t)idx * 8) = v;
}

__global__ void pack_w_kernel(const float* __restrict__ W, f16* __restrict__ Wp) {
    int idx = blockIdx.x * 256 + threadIdx.x;      // 98304
    int l  = idx & 63;
    int kt = (idx >> 6) & 7;
    int r  = idx >> 9;
    int g  = r % 3, jb = r / 3;
    int col = g * NH + jb * 16 + (l & 15);
    int k0  = kt * 32 + (l >> 4) * 8;
    f16x8 v;
#pragma unroll
    for (int e = 0; e < 8; ++e) v[e] = (f16)W[(size_t)(k0 + e) * NG + col];
    *(f16x8*)(Wp + (size_t)idx * 8) = v;
}

// ---- prep: pack x [B,T,D] f32 -> A-fragment-layout f16 ----
__global__ void pack_x_kernel(const float* __restrict__ x, f16* __restrict__ Xp) {
    int idx = blockIdx.x * 256 + threadIdx.x;      // 1048576
    int k8 = idx & 31;
    int t  = (idx >> 5) & 511;
    int b  = idx >> 14;
    const float* p = x + ((size_t)b * NT + t) * ND + k8 * 8;
    f32x4 a0 = *(const f32x4*)p;
    f32x4 a1 = *(const f32x4*)(p + 4);
    f16x8 v;
#pragma unroll
    for (int e = 0; e < 4; ++e) { v[e] = (f16)a0[e]; v[4 + e] = (f16)a1[e]; }
    int bb = b >> 4, lrow = b & 15;
    int w = k8 >> 3, m = (k8 >> 2) & 1, lchunk = k8 & 3;
    int l = lchunk * 16 + lrow;
    *(f16x8*)(Xp + (((((size_t)t * 4 + bb) * 4 + w) * 2 + m) * 64 + l) * 8) = v;
}

// bs[0..H): bi_z+br_z ; bs[H..2H): bi_r+br_r ; bs[2H..3H): bi_h ; bs[3H..4H): br_h
__global__ void bias_kernel(const float* __restrict__ bi, const float* __restrict__ br,
                            float* __restrict__ bs) {
    int j = threadIdx.x;  // 1024
    bs[j]          = bi[j] + br[j];
    bs[NH + j]     = bi[NH + j] + br[NH + j];
    bs[2 * NH + j] = bi[2 * NH + j];
    bs[3 * NH + j] = br[2 * NH + j];
}

// coherence-point (LLC) accessors
__device__ __forceinline__ void llc_store16(void* p, u32x4 v) {
    asm volatile("global_store_dwordx4 %0, %1, off sc0 sc1" :: "v"(p), "v"(v));
}
template<int OFF>
__device__ __forceinline__ u32x4 llc_load16o(const unsigned int* p) {
    u32x4 r;
    asm volatile("global_load_dwordx4 %0, %1, off offset:%2 sc0 sc1"
                 : "=v"(r) : "v"(p), "i"(OFF));
    return r;
}

// seq nibble from a packet's dword3 (2 LSBs of each f16 half)
__device__ __forceinline__ unsigned nib(unsigned d3) {
    return (d3 & 3u) | ((d3 >> 14) & 0xCu);
}
// packet -> MFMA fragment (mask the stolen seq bits out of dword3)
__device__ __forceinline__ f16x8 frag(u32x4 p) {
    union { unsigned u[4]; f16x8 v; } U;
    U.u[0] = p.x; U.u[1] = p.y; U.u[2] = p.z; U.u[3] = p.w & 0xFFFCFFFCu;
    return U.v;
}

// quantize own h to f16, gather 8 row-neighbors via shuffles, embed seq nibble
// in dword3 LSBs, lanes tid%8==0 store the 16B packet (fire-and-forget).
__device__ __forceinline__ void publish_h(float hn, int tid, unsigned seqn,
                                          unsigned int* dst) {
    union { f16 h; unsigned short us; } cv; cv.h = (f16)hn;
    unsigned u = cv.us;
    int l = tid & 63;
    int base = (l & 48) | (((l >> 3) & 1) << 3);
    unsigned f0 = (unsigned)__shfl((int)u, base + 0);
    unsigned f1 = (unsigned)__shfl((int)u, base + 1);
    unsigned f2 = (unsigned)__shfl((int)u, base + 2);
    unsigned f3 = (unsigned)__shfl((int)u, base + 3);
    unsigned f4 = (unsigned)__shfl((int)u, base + 4);
    unsigned f5 = (unsigned)__shfl((int)u, base + 5);
    unsigned f6 = (unsigned)__shfl((int)u, base + 6);
    unsigned f7 = (unsigned)__shfl((int)u, base + 7);
    u32x4 d;
    d.x = f0 | (f1 << 16);
    d.y = f2 | (f3 << 16);
    d.z = f4 | (f5 << 16);
    d.w = (f6 & 0xFFFCu) | ((f7 & 0xFFFCu) << 16)
        | (seqn & 3u) | ((seqn & 0xCu) << 14);
    if ((tid & 7) == 0) llc_store16(dst, d);
}

#define MFMA(a, b, c) __builtin_amdgcn_mfma_f32_16x16x32_f16(a, b, c, 0, 0, 0)

__global__ __launch_bounds__(256, 1) void gru_kernel(
    const float* __restrict__ h0,       // [B,H] f32
    const f16*   __restrict__ Up,
    const f16*   __restrict__ Wp,
    const float* __restrict__ bs,       // [4][H]
    const f16*   __restrict__ Xp,       // packed x fragments
    unsigned int* __restrict__ hpk,     // packet buffer (2 parities)
    float* __restrict__ out)            // y [B,T,H] then state [B,H]
{
    const int tid  = threadIdx.x;
    const int wgid = blockIdx.x;
    const int bb = (wgid >> 1) & 3;
    const int jb = ((wgid & 1) << 5) | (wgid >> 3);
    const int w  = tid >> 6;
    const int l  = tid & 63;

    __shared__ float red[2][4][4][256];   // [parity][wave][tile][lane*4+i]

    // ---- gates mapping ----
    const int gb = tid >> 4, gj = tid & 15;
    const int bglob = bb * 16 + gb;
    const int jglob = jb * 16 + gj;
    float hown = h0[(size_t)bglob * NH + jglob];

    // ---- publish destinations (per parity) ----
    unsigned int* pub0 = hpk +
        ((size_t)(bb * 2 + 0) * 2048 + (jb >> 4) * 512 + ((jb & 15) >> 1) * 64 +
         ((jb & 1) * 2 + ((tid >> 3) & 1)) * 16 + gb) * 4;
    unsigned int* pub1 = pub0 + 8192;

    // publish h^0 (parity 0, nibble 1) before anything slow
    publish_h(hown, tid, 1u, pub0);

    // ---- persistent B fragments in registers ----
    f16x8 uz[8], ur[8], uh[8], wz[2], wr[2], wh[2];
    {
        const f16* ub = Up + (size_t)jb * 3 * 32 * 512;
#pragma unroll
        for (int q = 0; q < 8; ++q) {
            int kt = w * 8 + q;
            uz[q] = *(const f16x8*)(ub + ((size_t)(0 * 32 + kt) * 64 + l) * 8);
            ur[q] = *(const f16x8*)(ub + ((size_t)(1 * 32 + kt) * 64 + l) * 8);
            uh[q] = *(const f16x8*)(ub + ((size_t)(2 * 32 + kt) * 64 + l) * 8);
        }
        const f16* wb = Wp + (size_t)jb * 3 * 8 * 512;
#pragma unroll
        for (int m = 0; m < 2; ++m) {
            int kt = w * 2 + m;
            wz[m] = *(const f16x8*)(wb + ((size_t)(0 * 8 + kt) * 64 + l) * 8);
            wr[m] = *(const f16x8*)(wb + ((size_t)(1 * 8 + kt) * 64 + l) * 8);
            wh[m] = *(const f16x8*)(wb + ((size_t)(2 * 8 + kt) * 64 + l) * 8);
        }
    }

    const float bz  = bs[jglob];
    const float brg = bs[NH + jglob];
    const float bih = bs[2 * NH + jglob];
    const float brh = bs[3 * NH + jglob];

    // ---- consumer poll bases (parity 0/1; second half for q>=4) ----
    const unsigned int* hq0 = hpk + ((size_t)(bb * 2 + 0) * 2048 + w * 512 + l) * 4;
    const unsigned int* hq1 = hq0 + 8192;
    const unsigned int* hq0b = hq0 + 1024;
    const unsigned int* hq1b = hq1 + 1024;

    // ---- x(0) fragment prologue loads ----
    f16x8 xA0, xA1, xB0, xB1;
    {
        const f16* p = Xp + (((size_t)0 * 4 + bb) * 4 + w) * 1024 + l * 8;
        xA0 = *(const f16x8*)p;
        xA1 = *(const f16x8*)(p + 512);
    }

    float ybuf[8];

    for (int tb = 0; tb < NT / 8; ++tb) {
#pragma unroll
        for (int tt = 0; tt < 8; ++tt) {
            const int t = tb * 8 + tt;
            const bool even = ((tt & 1) == 0);   // parity of h^t

            // ---- x-only MFMAs first (independent of h^t) ----
            f16x8 ax0 = even ? xA0 : xB0;
            f16x8 ax1 = even ? xA1 : xB1;
            f32x4 acc_z = {0,0,0,0}, acc_r = {0,0,0,0};
            f32x4 acc_xh = {0,0,0,0}, acc_rh = {0,0,0,0};
            acc_z  = MFMA(ax0, wz[0], acc_z);
            acc_r  = MFMA(ax0, wr[0], acc_r);
            acc_xh = MFMA(ax0, wh[0], acc_xh);
            acc_z  = MFMA(ax1, wz[1], acc_z);
            acc_r  = MFMA(ax1, wr[1], acc_r);
            acc_xh = MFMA(ax1, wh[1], acc_xh);
            __builtin_amdgcn_sched_barrier(0);

            // ---- poll h^t packets: full-packet spin, passing iteration IS data;
            //      vmcnt(0) drains ONLY packet loads (x issue moved post-detect) ----
            const unsigned int* b0 = even ? hq0 : hq1;
            const unsigned int* b1 = even ? hq0b : hq1b;
            const unsigned T1n = (unsigned)(t + 1) & 15u;
            u32x4 p0, p1, p2, p3, p4, p5, p6, p7;
            int it = 0;
            while (true) {
                p0 = llc_load16o<0>(b0);
                p1 = llc_load16o<1024>(b0);
                p2 = llc_load16o<2048>(b0);
                p3 = llc_load16o<3072>(b0);
                p4 = llc_load16o<0>(b1);
                p5 = llc_load16o<1024>(b1);
                p6 = llc_load16o<2048>(b1);
                p7 = llc_load16o<3072>(b1);
                asm volatile("s_waitcnt vmcnt(0)" ::: "memory");
                __builtin_amdgcn_sched_barrier(0);
                bool ok = (nib(p0.w) == T1n) & (nib(p1.w) == T1n)
                        & (nib(p2.w) == T1n) & (nib(p3.w) == T1n)
                        & (nib(p4.w) == T1n) & (nib(p5.w) == T1n)
                        & (nib(p6.w) == T1n) & (nib(p7.w) == T1n);
                if (__all((int)ok)) break;
                if (++it > 20000) break;               // watchdog: absmax flags it
                if (it > 3) __builtin_amdgcn_s_sleep(1);
            }
            __builtin_amdgcn_sched_barrier(0);

            // ---- issue x(t+1) loads now (consumed next step; ~full step to land) ----
            {
                const int tn = (t < NT - 1) ? t + 1 : t;
                const f16* p = Xp + (((size_t)tn * 4 + bb) * 4 + w) * 1024 + l * 8;
                if (even) { xB0 = *(const f16x8*)p; xB1 = *(const f16x8*)(p + 512); }
                else      { xA0 = *(const f16x8*)p; xA1 = *(const f16x8*)(p + 512); }
            }

            // ---- U-part MFMAs: packets ARE the fragments ----
            f16x8 au;
            au = frag(p0);
            acc_z = MFMA(au, uz[0], acc_z); acc_r = MFMA(au, ur[0], acc_r); acc_rh = MFMA(au, uh[0], acc_rh);
            au = frag(p1);
            acc_z = MFMA(au, uz[1], acc_z); acc_r = MFMA(au, ur[1], acc_r); acc_rh = MFMA(au, uh[1], acc_rh);
            au = frag(p2);
            acc_z = MFMA(au, uz[2], acc_z); acc_r = MFMA(au, ur[2], acc_r); acc_rh = MFMA(au, uh[2], acc_rh);
            au = frag(p3);
            acc_z = MFMA(au, uz[3], acc_z); acc_r = MFMA(au, ur[3], acc_r); acc_rh = MFMA(au, uh[3], acc_rh);
            au = frag(p4);
            acc_z = MFMA(au, uz[4], acc_z); acc_r = MFMA(au, ur[4], acc_r); acc_rh = MFMA(au, uh[4], acc_rh);
            au = frag(p5);
            acc_z = MFMA(au, uz[5], acc_z); acc_r = MFMA(au, ur[5], acc_r); acc_rh = MFMA(au, uh[5], acc_rh);
            au = frag(p6);
            acc_z = MFMA(au, uz[6], acc_z); acc_r = MFMA(au, ur[6], acc_r); acc_rh = MFMA(au, uh[6], acc_rh);
            au = frag(p7);
            acc_z = MFMA(au, uz[7], acc_z); acc_r = MFMA(au, ur[7], acc_r); acc_rh = MFMA(au, uh[7], acc_rh);

            // ---- cross-wave reduction via LDS (parity dbuf, 1 barrier) ----
            *(f32x4*)&red[tt & 1][w][0][l * 4] = acc_z;
            *(f32x4*)&red[tt & 1][w][1][l * 4] = acc_r;
            *(f32x4*)&red[tt & 1][w][2][l * 4] = acc_xh;
            *(f32x4*)&red[tt & 1][w][3][l * 4] = acc_rh;
            __syncthreads();

            const int li = ((((gb >> 2) << 4) | gj) << 2) + (gb & 3);
            float sz = 0.f, sr = 0.f, sxh = 0.f, srh = 0.f;
#pragma unroll
            for (int ww = 0; ww < 4; ++ww) {
                sz  += red[tt & 1][ww][0][li];
                sr  += red[tt & 1][ww][1][li];
                sxh += red[tt & 1][ww][2][li];
                srh += red[tt & 1][ww][3][li];
            }

            // ---- gates ----
            float zg = 1.f / (1.f + __expf(-(sz + bz)));
            float rg = 1.f / (1.f + __expf(-(sr + brg)));
            float ta = sxh + bih + rg * (srh + brh);
            ta = fminf(10.f, fmaxf(-10.f, ta));
            float e2 = __expf(2.f * ta);
            float hh = (e2 - 1.f) / (e2 + 1.f);
            float hn = zg * hown + (1.f - zg) * hh;
            hown = hn;
            ybuf[tt] = hn;

            // ---- publish h^{t+1}: fire-and-forget packets ----
            publish_h(hn, tid, (unsigned)(t + 2) & 15u, even ? pub1 : pub0);
        }

        // ---- burst 8 steps of y (off critical chain) ----
        float* yb = out + ((size_t)bglob * NT + tb * 8) * NH + jglob;
#pragma unroll
        for (int tt = 0; tt < 8; ++tt)
            __builtin_nontemporal_store(ybuf[tt], yb + (size_t)tt * NH);
    }

    // final state
    out[(size_t)NB * NT * NH + (size_t)bglob * NH + jglob] = hown;
}

extern "C" void kernel_launch(void* const* d_in, const int* in_sizes, int n_in,
                              void* d_out, int out_size, void* d_ws, size_t ws_size,
                              hipStream_t stream) {
    const float* x  = (const float*)d_in[0];
    const float* h0 = (const float*)d_in[1];
    const float* W  = (const float*)d_in[2];
    const float* U  = (const float*)d_in[3];
    const float* bi = (const float*)d_in[4];
    const float* br = (const float*)d_in[5];
    float* out = (float*)d_out;

    char* ws = (char*)d_ws;
    f16* Up   = (f16*)ws;                                // 6,291,456 B
    f16* Wp   = (f16*)(ws + 6291456);                    // 1,572,864 B
    float* bs = (float*)(ws + 7864320);                  // 16 KB
    f16* Xp   = (f16*)(ws + 7880704);                    // 16,777,216 B
    unsigned int* hpk = (unsigned int*)(ws + 24657920);  // 256 KB packets

    (void)hipMemsetAsync(hpk, 0, 262144, stream);        // nibble 0 -> not ready
    pack_u_kernel<<<1536, 256, 0, stream>>>(U, Up);
    pack_w_kernel<<<384, 256, 0, stream>>>(W, Wp);
    pack_x_kernel<<<4096, 256, 0, stream>>>(x, Xp);
    bias_kernel<<<1, 1024, 0, stream>>>(bi, br, bs);

    void* args[] = { (void*)&h0, (void*)&Up, (void*)&Wp, (void*)&bs,
                     (void*)&Xp, (void*)&hpk, (void*)&out };
    hipError_t err = hipLaunchCooperativeKernel((const void*)gru_kernel, dim3(256),
                                                dim3(256), args, 0, stream);
    if (err != hipSuccess) {
        gru_kernel<<<dim3(256), dim3(256), 0, stream>>>(h0, Up, Wp, bs, Xp, hpk, out);
    }
}

// Round 18
// 964.684 us; speedup vs baseline: 1.6484x; 1.6484x over previous
//
#include <hip/hip_runtime.h>
#include <hip/hip_fp16.h>

// GRU (Keras reset_after=True), B=64 T=512 D=256 H=1024.
// Persistent kernel, 256 WGs (1/CU), weights register-resident.
// Single-hop packet protocol (LLC/sc0sc1): packets are 8 native f16 + 4-bit
// seq nibble stolen from dword3 LSBs; full-packet serial spin where the
// passing iteration IS the data. CHAMPION CONFIG (R13, 967us) restored
// verbatim: x(t+1) issued BEFORE the poll (completes under sweep RTTs, so
// the per-step __syncthreads vmcnt(0) drain never stalls on it -- R17
// proved moving it costs +65%).

#define NB 64
#define NT 512
#define ND 256
#define NH 1024
#define NG 3072  // 3H

typedef _Float16 f16;
typedef __attribute__((ext_vector_type(8))) _Float16 f16x8;
typedef __attribute__((ext_vector_type(4))) float f32x4;
typedef __attribute__((ext_vector_type(4))) unsigned int u32x4;

// ---- prep: pack U [H,3H] f32 -> B-fragment-layout f16 ----
__global__ void pack_u_kernel(const float* __restrict__ U, f16* __restrict__ Up) {
    int idx = blockIdx.x * 256 + threadIdx.x;      // 393216
    int l  = idx & 63;
    int kt = (idx >> 6) & 31;
    int r  = idx >> 11;                            // jb*3 + g
    int g  = r % 3, jb = r / 3;
    int col = g * NH + jb * 16 + (l & 15);
    int k0  = kt * 32 + (l >> 4) * 8;
    f16x8 v;
#pragma unroll
    for (int e = 0; e < 8; ++e) v[e] = (f16)U[(size_t)(k0 + e) * NG + col];
    *(f16x8*)(Up + (size_t)idx * 8) = v;
}

__global__ void pack_w_kernel(const float* __restrict__ W, f16* __restrict__ Wp) {
    int idx = blockIdx.x * 256 + threadIdx.x;      // 98304
    int l  = idx & 63;
    int kt = (idx >> 6) & 7;
    int r  = idx >> 9;
    int g  = r % 3, jb = r / 3;
    int col = g * NH + jb * 16 + (l & 15);
    int k0  = kt * 32 + (l >> 4) * 8;
    f16x8 v;
#pragma unroll
    for (int e = 0; e < 8; ++e) v[e] = (f16)W[(size_t)(k0 + e) * NG + col];
    *(f16x8*)(Wp + (size_t)idx * 8) = v;
}

// ---- prep: pack x [B,T,D] f32 -> A-fragment-layout f16 ----
__global__ void pack_x_kernel(const float* __restrict__ x, f16* __restrict__ Xp) {
    int idx = blockIdx.x * 256 + threadIdx.x;      // 1048576
    int k8 = idx & 31;
    int t  = (idx >> 5) & 511;
    int b  = idx >> 14;
    const float* p = x + ((size_t)b * NT + t) * ND + k8 * 8;
    f32x4 a0 = *(const f32x4*)p;
    f32x4 a1 = *(const f32x4*)(p + 4);
    f16x8 v;
#pragma unroll
    for (int e = 0; e < 4; ++e) { v[e] = (f16)a0[e]; v[4 + e] = (f16)a1[e]; }
    int bb = b >> 4, lrow = b & 15;
    int w = k8 >> 3, m = (k8 >> 2) & 1, lchunk = k8 & 3;
    int l = lchunk * 16 + lrow;
    *(f16x8*)(Xp + (((((size_t)t * 4 + bb) * 4 + w) * 2 + m) * 64 + l) * 8) = v;
}

// bs[0..H): bi_z+br_z ; bs[H..2H): bi_r+br_r ; bs[2H..3H): bi_h ; bs[3H..4H): br_h
__global__ void bias_kernel(const float* __restrict__ bi, const float* __restrict__ br,
                            float* __restrict__ bs) {
    int j = threadIdx.x;  // 1024
    bs[j]          = bi[j] + br[j];
    bs[NH + j]     = bi[NH + j] + br[NH + j];
    bs[2 * NH + j] = bi[2 * NH + j];
    bs[3 * NH + j] = br[2 * NH + j];
}

// coherence-point (LLC) accessors
__device__ __forceinline__ void llc_store16(void* p, u32x4 v) {
    asm volatile("global_store_dwordx4 %0, %1, off sc0 sc1" :: "v"(p), "v"(v));
}
template<int OFF>
__device__ __forceinline__ u32x4 llc_load16o(const unsigned int* p) {
    u32x4 r;
    asm volatile("global_load_dwordx4 %0, %1, off offset:%2 sc0 sc1"
                 : "=v"(r) : "v"(p), "i"(OFF));
    return r;
}

// seq nibble from a packet's dword3 (2 LSBs of each f16 half)
__device__ __forceinline__ unsigned nib(unsigned d3) {
    return (d3 & 3u) | ((d3 >> 14) & 0xCu);
}
// packet -> MFMA fragment (mask the stolen seq bits out of dword3)
__device__ __forceinline__ f16x8 frag(u32x4 p) {
    union { unsigned u[4]; f16x8 v; } U;
    U.u[0] = p.x; U.u[1] = p.y; U.u[2] = p.z; U.u[3] = p.w & 0xFFFCFFFCu;
    return U.v;
}

// quantize own h to f16, gather 8 row-neighbors via shuffles, embed seq nibble
// in dword3 LSBs, lanes tid%8==0 store the 16B packet (fire-and-forget).
__device__ __forceinline__ void publish_h(float hn, int tid, unsigned seqn,
                                          unsigned int* dst) {
    union { f16 h; unsigned short us; } cv; cv.h = (f16)hn;
    unsigned u = cv.us;
    int l = tid & 63;
    int base = (l & 48) | (((l >> 3) & 1) << 3);
    unsigned f0 = (unsigned)__shfl((int)u, base + 0);
    unsigned f1 = (unsigned)__shfl((int)u, base + 1);
    unsigned f2 = (unsigned)__shfl((int)u, base + 2);
    unsigned f3 = (unsigned)__shfl((int)u, base + 3);
    unsigned f4 = (unsigned)__shfl((int)u, base + 4);
    unsigned f5 = (unsigned)__shfl((int)u, base + 5);
    unsigned f6 = (unsigned)__shfl((int)u, base + 6);
    unsigned f7 = (unsigned)__shfl((int)u, base + 7);
    u32x4 d;
    d.x = f0 | (f1 << 16);
    d.y = f2 | (f3 << 16);
    d.z = f4 | (f5 << 16);
    d.w = (f6 & 0xFFFCu) | ((f7 & 0xFFFCu) << 16)
        | (seqn & 3u) | ((seqn & 0xCu) << 14);
    if ((tid & 7) == 0) llc_store16(dst, d);
}

#define MFMA(a, b, c) __builtin_amdgcn_mfma_f32_16x16x32_f16(a, b, c, 0, 0, 0)

__global__ __launch_bounds__(256, 1) void gru_kernel(
    const float* __restrict__ h0,       // [B,H] f32
    const f16*   __restrict__ Up,
    const f16*   __restrict__ Wp,
    const float* __restrict__ bs,       // [4][H]
    const f16*   __restrict__ Xp,       // packed x fragments
    unsigned int* __restrict__ hpk,     // packet buffer (2 parities)
    float* __restrict__ out)            // y [B,T,H] then state [B,H]
{
    const int tid  = threadIdx.x;
    const int wgid = blockIdx.x;
    const int bb = (wgid >> 1) & 3;
    const int jb = ((wgid & 1) << 5) | (wgid >> 3);
    const int w  = tid >> 6;
    const int l  = tid & 63;

    __shared__ float red[2][4][4][256];   // [parity][wave][tile][lane*4+i]

    // ---- gates mapping ----
    const int gb = tid >> 4, gj = tid & 15;
    const int bglob = bb * 16 + gb;
    const int jglob = jb * 16 + gj;
    float hown = h0[(size_t)bglob * NH + jglob];

    // ---- publish destinations (per parity) ----
    unsigned int* pub0 = hpk +
        ((size_t)(bb * 2 + 0) * 2048 + (jb >> 4) * 512 + ((jb & 15) >> 1) * 64 +
         ((jb & 1) * 2 + ((tid >> 3) & 1)) * 16 + gb) * 4;
    unsigned int* pub1 = pub0 + 8192;

    // publish h^0 (parity 0, nibble 1) before anything slow
    publish_h(hown, tid, 1u, pub0);

    // ---- persistent B fragments in registers ----
    f16x8 uz[8], ur[8], uh[8], wz[2], wr[2], wh[2];
    {
        const f16* ub = Up + (size_t)jb * 3 * 32 * 512;
#pragma unroll
        for (int q = 0; q < 8; ++q) {
            int kt = w * 8 + q;
            uz[q] = *(const f16x8*)(ub + ((size_t)(0 * 32 + kt) * 64 + l) * 8);
            ur[q] = *(const f16x8*)(ub + ((size_t)(1 * 32 + kt) * 64 + l) * 8);
            uh[q] = *(const f16x8*)(ub + ((size_t)(2 * 32 + kt) * 64 + l) * 8);
        }
        const f16* wb = Wp + (size_t)jb * 3 * 8 * 512;
#pragma unroll
        for (int m = 0; m < 2; ++m) {
            int kt = w * 2 + m;
            wz[m] = *(const f16x8*)(wb + ((size_t)(0 * 8 + kt) * 64 + l) * 8);
            wr[m] = *(const f16x8*)(wb + ((size_t)(1 * 8 + kt) * 64 + l) * 8);
            wh[m] = *(const f16x8*)(wb + ((size_t)(2 * 8 + kt) * 64 + l) * 8);
        }
    }

    const float bz  = bs[jglob];
    const float brg = bs[NH + jglob];
    const float bih = bs[2 * NH + jglob];
    const float brh = bs[3 * NH + jglob];

    // ---- consumer poll bases (parity 0/1; second half for q>=4) ----
    const unsigned int* hq0 = hpk + ((size_t)(bb * 2 + 0) * 2048 + w * 512 + l) * 4;
    const unsigned int* hq1 = hq0 + 8192;
    const unsigned int* hq0b = hq0 + 1024;
    const unsigned int* hq1b = hq1 + 1024;

    // ---- x(0) fragment prologue loads ----
    f16x8 xA0, xA1, xB0, xB1;
    {
        const f16* p = Xp + (((size_t)0 * 4 + bb) * 4 + w) * 1024 + l * 8;
        xA0 = *(const f16x8*)p;
        xA1 = *(const f16x8*)(p + 512);
    }

    float ybuf[8];

    for (int tb = 0; tb < NT / 8; ++tb) {
#pragma unroll
        for (int tt = 0; tt < 8; ++tt) {
            const int t = tb * 8 + tt;
            const bool even = ((tt & 1) == 0);   // parity of h^t

            // ---- x-only MFMAs first (independent of h^t) ----
            f16x8 ax0 = even ? xA0 : xB0;
            f16x8 ax1 = even ? xA1 : xB1;
            f32x4 acc_z = {0,0,0,0}, acc_r = {0,0,0,0};
            f32x4 acc_xh = {0,0,0,0}, acc_rh = {0,0,0,0};
            acc_z  = MFMA(ax0, wz[0], acc_z);
            acc_r  = MFMA(ax0, wr[0], acc_r);
            acc_xh = MFMA(ax0, wh[0], acc_xh);
            acc_z  = MFMA(ax1, wz[1], acc_z);
            acc_r  = MFMA(ax1, wr[1], acc_r);
            acc_xh = MFMA(ax1, wh[1], acc_xh);
            __builtin_amdgcn_sched_barrier(0);

            // ---- issue x(t+1) loads BEFORE the poll (complete under 1st RTT) ----
            {
                const int tn = (t < NT - 1) ? t + 1 : t;
                const f16* p = Xp + (((size_t)tn * 4 + bb) * 4 + w) * 1024 + l * 8;
                if (even) { xB0 = *(const f16x8*)p; xB1 = *(const f16x8*)(p + 512); }
                else      { xA0 = *(const f16x8*)p; xA1 = *(const f16x8*)(p + 512); }
            }

            // ---- poll h^t packets: full-packet spin, passing iteration IS data ----
            const unsigned int* b0 = even ? hq0 : hq1;
            const unsigned int* b1 = even ? hq0b : hq1b;
            const unsigned T1n = (unsigned)(t + 1) & 15u;
            u32x4 p0, p1, p2, p3, p4, p5, p6, p7;
            int it = 0;
            while (true) {
                p0 = llc_load16o<0>(b0);
                p1 = llc_load16o<1024>(b0);
                p2 = llc_load16o<2048>(b0);
                p3 = llc_load16o<3072>(b0);
                p4 = llc_load16o<0>(b1);
                p5 = llc_load16o<1024>(b1);
                p6 = llc_load16o<2048>(b1);
                p7 = llc_load16o<3072>(b1);
                asm volatile("s_waitcnt vmcnt(0)" ::: "memory");
                __builtin_amdgcn_sched_barrier(0);
                bool ok = (nib(p0.w) == T1n) & (nib(p1.w) == T1n)
                        & (nib(p2.w) == T1n) & (nib(p3.w) == T1n)
                        & (nib(p4.w) == T1n) & (nib(p5.w) == T1n)
                        & (nib(p6.w) == T1n) & (nib(p7.w) == T1n);
                if (__all((int)ok)) break;
                if (++it > 20000) break;               // watchdog: absmax flags it
                if (it > 3) __builtin_amdgcn_s_sleep(1);
            }
            __builtin_amdgcn_sched_barrier(0);

            // ---- U-part MFMAs: packets ARE the fragments ----
            f16x8 au;
            au = frag(p0);
            acc_z = MFMA(au, uz[0], acc_z); acc_r = MFMA(au, ur[0], acc_r); acc_rh = MFMA(au, uh[0], acc_rh);
            au = frag(p1);
            acc_z = MFMA(au, uz[1], acc_z); acc_r = MFMA(au, ur[1], acc_r); acc_rh = MFMA(au, uh[1], acc_rh);
            au = frag(p2);
            acc_z = MFMA(au, uz[2], acc_z); acc_r = MFMA(au, ur[2], acc_r); acc_rh = MFMA(au, uh[2], acc_rh);
            au = frag(p3);
            acc_z = MFMA(au, uz[3], acc_z); acc_r = MFMA(au, ur[3], acc_r); acc_rh = MFMA(au, uh[3], acc_rh);
            au = frag(p4);
            acc_z = MFMA(au, uz[4], acc_z); acc_r = MFMA(au, ur[4], acc_r); acc_rh = MFMA(au, uh[4], acc_rh);
            au = frag(p5);
            acc_z = MFMA(au, uz[5], acc_z); acc_r = MFMA(au, ur[5], acc_r); acc_rh = MFMA(au, uh[5], acc_rh);
            au = frag(p6);
            acc_z = MFMA(au, uz[6], acc_z); acc_r = MFMA(au, ur[6], acc_r); acc_rh = MFMA(au, uh[6], acc_rh);
            au = frag(p7);
            acc_z = MFMA(au, uz[7], acc_z); acc_r = MFMA(au, ur[7], acc_r); acc_rh = MFMA(au, uh[7], acc_rh);

            // ---- cross-wave reduction via LDS (parity dbuf, 1 barrier) ----
            *(f32x4*)&red[tt & 1][w][0][l * 4] = acc_z;
            *(f32x4*)&red[tt & 1][w][1][l * 4] = acc_r;
            *(f32x4*)&red[tt & 1][w][2][l * 4] = acc_xh;
            *(f32x4*)&red[tt & 1][w][3][l * 4] = acc_rh;
            __syncthreads();

            const int li = ((((gb >> 2) << 4) | gj) << 2) + (gb & 3);
            float sz = 0.f, sr = 0.f, sxh = 0.f, srh = 0.f;
#pragma unroll
            for (int ww = 0; ww < 4; ++ww) {
                sz  += red[tt & 1][ww][0][li];
                sr  += red[tt & 1][ww][1][li];
                sxh += red[tt & 1][ww][2][li];
                srh += red[tt & 1][ww][3][li];
            }

            // ---- gates ----
            float zg = 1.f / (1.f + __expf(-(sz + bz)));
            float rg = 1.f / (1.f + __expf(-(sr + brg)));
            float ta = sxh + bih + rg * (srh + brh);
            ta = fminf(10.f, fmaxf(-10.f, ta));
            float e2 = __expf(2.f * ta);
            float hh = (e2 - 1.f) / (e2 + 1.f);
            float hn = zg * hown + (1.f - zg) * hh;
            hown = hn;
            ybuf[tt] = hn;

            // ---- publish h^{t+1}: fire-and-forget packets ----
            publish_h(hn, tid, (unsigned)(t + 2) & 15u, even ? pub1 : pub0);
        }

        // ---- burst 8 steps of y (off critical chain) ----
        float* yb = out + ((size_t)bglob * NT + tb * 8) * NH + jglob;
#pragma unroll
        for (int tt = 0; tt < 8; ++tt)
            __builtin_nontemporal_store(ybuf[tt], yb + (size_t)tt * NH);
    }

    // final state
    out[(size_t)NB * NT * NH + (size_t)bglob * NH + jglob] = hown;
}

extern "C" void kernel_launch(void* const* d_in, const int* in_sizes, int n_in,
                              void* d_out, int out_size, void* d_ws, size_t ws_size,
                              hipStream_t stream) {
    const float* x  = (const float*)d_in[0];
    const float* h0 = (const float*)d_in[1];
    const float* W  = (const float*)d_in[2];
    const float* U  = (const float*)d_in[3];
    const float* bi = (const float*)d_in[4];
    const float* br = (const float*)d_in[5];
    float* out = (float*)d_out;

    char* ws = (char*)d_ws;
    f16* Up   = (f16*)ws;                                // 6,291,456 B
    f16* Wp   = (f16*)(ws + 6291456);                    // 1,572,864 B
    float* bs = (float*)(ws + 7864320);                  // 16 KB
    f16* Xp   = (f16*)(ws + 7880704);                    // 16,777,216 B
    unsigned int* hpk = (unsigned int*)(ws + 24657920);  // 256 KB packets

    (void)hipMemsetAsync(hpk, 0, 262144, stream);        // nibble 0 -> not ready
    pack_u_kernel<<<1536, 256, 0, stream>>>(U, Up);
    pack_w_kernel<<<384, 256, 0, stream>>>(W, Wp);
    pack_x_kernel<<<4096, 256, 0, stream>>>(x, Xp);
    bias_kernel<<<1, 1024, 0, stream>>>(bi, br, bs);

    void* args[] = { (void*)&h0, (void*)&Up, (void*)&Wp, (void*)&bs,
                     (void*)&Xp, (void*)&hpk, (void*)&out };
    hipError_t err = hipLaunchCooperativeKernel((const void*)gru_kernel, dim3(256),
                                                dim3(256), args, 0, stream);
    if (err != hipSuccess) {
        gru_kernel<<<dim3(256), dim3(256), 0, stream>>>(h0, Up, Wp, bs, Xp, hpk, out);
    }
}